// Round 18
// baseline (426.525 us; speedup 1.0000x reference)
//
#include <hip/hip_runtime.h>
#include <cstdint>

// ---- problem constants ----
#define B_SZ   64
#define SEQ    197
#define DIM    768
#define NHEAD  12
#define HDK    64
#define MLP_D  3072
#define RH_D   512
#define RANK_D 256
#define NEXP   3
#define TOK    (B_SZ*SEQ)   // 12608

typedef unsigned short u16;
typedef __attribute__((ext_vector_type(8))) short s16x8;
typedef __attribute__((ext_vector_type(4))) float f32x4;

static __device__ __forceinline__ u16 f2bf(float f) {
  unsigned u = __builtin_bit_cast(unsigned, f);
  u = u + 0x7FFFu + ((u >> 16) & 1u);
  return (u16)(u >> 16);
}

static __device__ __forceinline__ f32x4 mfma16(s16x8 a, s16x8 b, f32x4 c) {
  return __builtin_amdgcn_mfma_f32_16x16x32_bf16(a, b, c, 0, 0, 0);
}

// async global->LDS, 16B per lane; LDS dest must be wave-uniform base + lane*16
static __device__ __forceinline__ void gload16(const u16* g, u16* l) {
  __builtin_amdgcn_global_load_lds(
      (const __attribute__((address_space(1))) unsigned int*)(const void*)g,
      (__attribute__((address_space(3))) unsigned int*)(void*)l,
      16, 0, 0);
}

// fast GELU: x*sigmoid(2u), u = sqrt(2/pi)(x+0.044715x^3); |err|<=~3e-4
static __device__ __forceinline__ float gelu_fast(float v) {
  const float u2 = 2.f * v * (0.7978845608f + 0.0356774081f * v * v);
  return v / (1.f + __expf(-u2));
}

// ---- merged f32->bf16 convert for weights (x handled by ln_rows dual-out) ----
__global__ __launch_bounds__(256) void cvt_all(
    const float* __restrict__ s0, const float* __restrict__ s1,
    const float* __restrict__ s2, const float* __restrict__ s3,
    const float* __restrict__ s4, const float* __restrict__ s5,
    const float* __restrict__ s6,
    u16* d0, u16* d1, u16* d2, u16* d3, u16* d4, u16* d5, u16* d6)
{
  const long T4 = 7471104L / 4;
  for (long i = (long)blockIdx.x * 256 + threadIdx.x; i < T4; i += (long)gridDim.x * 256) {
    const long e = i * 4;
    const float* s; u16* d; long off;
    if      (e < 589824L)   { s = s0; d = d0; off = e; }
    else if (e < 1179648L)  { s = s1; d = d1; off = e - 589824L; }
    else if (e < 1769472L)  { s = s2; d = d2; off = e - 1179648L; }
    else if (e < 2359296L)  { s = s3; d = d3; off = e - 1769472L; }
    else if (e < 4718592L)  { s = s4; d = d4; off = e - 2359296L; }
    else if (e < 7077888L)  { s = s5; d = d5; off = e - 4718592L; }
    else                    { s = s6; d = d6; off = e - 7077888L; }
    float4 v = *(const float4*)(s + off);
    unsigned r0 = (unsigned)f2bf(v.x) | ((unsigned)f2bf(v.y) << 16);
    unsigned r1 = (unsigned)f2bf(v.z) | ((unsigned)f2bf(v.w) << 16);
    *(uint2*)(d + off) = make_uint2(r0, r1);
  }
}

__global__ void concat3(const float* __restrict__ a, const float* __restrict__ b,
                        const float* __restrict__ c, float* __restrict__ out) {
  int i = blockIdx.x * 256 + threadIdx.x;
  if (i < DIM) { out[i] = a[i]; out[DIM + i] = b[i]; out[2*DIM + i] = c[i]; }
}

// ---- LayerNorm over D=768, f32 in -> bf16 out (+ optional raw bf16 copy) ----
__global__ __launch_bounds__(256) void ln_rows(
    const float* __restrict__ x, const float* __restrict__ g,
    const float* __restrict__ bb, u16* __restrict__ out,
    u16* __restrict__ out_raw, int M)
{
  const int row = blockIdx.x * 4 + (threadIdx.x >> 6);
  const int lane = threadIdx.x & 63;
  if (row >= M) return;
  const float* xr = x + (long)row * DIM;
  float4 v[3];
  float s = 0.f, s2 = 0.f;
#pragma unroll
  for (int c = 0; c < 3; ++c) {
    v[c] = *(const float4*)(xr + c*256 + lane*4);
    s  += v[c].x + v[c].y + v[c].z + v[c].w;
    s2 += v[c].x*v[c].x + v[c].y*v[c].y + v[c].z*v[c].z + v[c].w*v[c].w;
  }
#pragma unroll
  for (int o = 1; o < 64; o <<= 1) { s += __shfl_xor(s, o); s2 += __shfl_xor(s2, o); }
  const float mean = s * (1.f/DIM);
  const float var  = s2 * (1.f/DIM) - mean*mean;
  const float rstd = rsqrtf(fmaxf(var, 0.f) + 1e-5f);
#pragma unroll
  for (int c = 0; c < 3; ++c) {
    const int idx = c*256 + lane*4;
    float4 gg = *(const float4*)(g + idx);
    float4 be = *(const float4*)(bb + idx);
    float y0 = (v[c].x - mean)*rstd*gg.x + be.x;
    float y1 = (v[c].y - mean)*rstd*gg.y + be.y;
    float y2 = (v[c].z - mean)*rstd*gg.z + be.z;
    float y3 = (v[c].w - mean)*rstd*gg.w + be.w;
    unsigned w0 = (unsigned)f2bf(y0) | ((unsigned)f2bf(y1) << 16);
    unsigned w1 = (unsigned)f2bf(y2) | ((unsigned)f2bf(y3) << 16);
    *(uint2*)(out + (long)row*DIM + idx) = make_uint2(w0, w1);
    if (out_raw) {
      unsigned q0 = (unsigned)f2bf(v[c].x) | ((unsigned)f2bf(v[c].y) << 16);
      unsigned q1 = (unsigned)f2bf(v[c].z) | ((unsigned)f2bf(v[c].w) << 16);
      *(uint2*)(out_raw + (long)row*DIM + idx) = make_uint2(q0, q1);
    }
  }
}

// ============================================================================
// 128x128-tile GEMM (r10-exact): 2-buffer issue-early pipeline, zero-conflict
// LDS swizzle, bijective XCD block swizzle. Used for r1, wo, fc2.
// ============================================================================
template<int ACT, bool HAS_RES, bool OUT_F32, bool OUT_BF16>
__global__ __launch_bounds__(256) void gemm_db(
    const u16* __restrict__ A, const u16* __restrict__ Bm,
    const float* __restrict__ bias, const float* __restrict__ res,
    float* __restrict__ Cf, u16* __restrict__ Cb,
    int ldc, int M, int N, int K)
{
  __shared__ __align__(16) u16 lA[2][128*32];
  __shared__ __align__(16) u16 lB[2][128*32];
  const int tid  = threadIdx.x;
  const int lane = tid & 63;
  const int wave = tid >> 6;

  const int nwg  = gridDim.x * gridDim.y;
  const int orig = blockIdx.y * gridDim.x + blockIdx.x;
  const int xcd  = orig & 7;
  const int q    = nwg >> 3, r = nwg & 7;
  const int nb   = (xcd < r ? xcd * (q + 1) : r * (q + 1) + (xcd - r) * q) + (orig >> 3);
  const int m0 = (nb / gridDim.x) * 128;
  const int n0 = (nb % gridDim.x) * 128;

  const int fr = lane & 15, fg = lane >> 4;
  const int wr = wave >> 1, wc = wave & 1;

  const int srow  = tid >> 2;
  const int scol  = (((tid & 3) ^ ((tid >> 3) & 3)) & 3) * 8;
  const int r0a = m0 + srow, r1a = m0 + 64 + srow;
  const u16* pa0 = A  + (long)((r0a < M) ? r0a : M - 1) * K + scol;
  const u16* pa1 = A  + (long)((r1a < M) ? r1a : M - 1) * K + scol;
  const u16* pb0 = Bm + (long)(n0 + srow) * K + scol;       // N mult of 128
  const u16* pb1 = Bm + (long)(n0 + 64 + srow) * K + scol;
  const int soff = tid * 8;

  auto STAGE = [&](int b, int kt) {
    gload16(pa0 + kt, &lA[b][soff]);
    gload16(pa1 + kt, &lA[b][soff + 2048]);
    gload16(pb0 + kt, &lB[b][soff]);
    gload16(pb1 + kt, &lB[b][soff + 2048]);
  };

  const int abase = fr * 32 + (((fg ^ (fr >> 1)) & 3) << 3);

  f32x4 acc[4][4] = {};
  const int NT = K >> 5;

  STAGE(0, 0);
  __syncthreads();
  int cur = 0;
#pragma unroll 1
  for (int t = 0; t < NT; ++t) {
    if (t + 1 < NT) STAGE(cur ^ 1, (t + 1) << 5);
    s16x8 af[4], bfr[4];
#pragma unroll
    for (int m = 0; m < 4; ++m) af[m]  = *(const s16x8*)&lA[cur][wr*2048 + m*512 + abase];
#pragma unroll
    for (int n = 0; n < 4; ++n) bfr[n] = *(const s16x8*)&lB[cur][wc*2048 + n*512 + abase];
#pragma unroll
    for (int m = 0; m < 4; ++m)
#pragma unroll
      for (int n = 0; n < 4; ++n)
        acc[m][n] = mfma16(af[m], bfr[n], acc[m][n]);
    __syncthreads();
    cur ^= 1;
  }

#pragma unroll
  for (int m = 0; m < 4; ++m) {
#pragma unroll
    for (int n = 0; n < 4; ++n) {
      const int col = n0 + wc*64 + n*16 + fr;
      const float bv = bias[col];
#pragma unroll
      for (int r2 = 0; r2 < 4; ++r2) {
        const int row = m0 + wr*64 + m*16 + fg*4 + r2;
        if (row < M) {
          float v = acc[m][n][r2] + bv;
          if constexpr (ACT == 1) v = gelu_fast(v);
          if constexpr (HAS_RES) v += res[(long)row * N + col];
          if constexpr (OUT_F32) Cf[(long)row * ldc + col] = v;
          if constexpr (OUT_BF16) Cb[(long)row * ldc + col] = f2bf(v);
        }
      }
    }
  }
}

// ============================================================================
// 128x256-tile GEMM for wide-N (fc1, qkv): r12-verified optimum (fc1 108us,
// MfmaUtil 23.4%, Occ 34%). 512 thr / 8 waves (2M x 4N), wave tile 64x64.
// ============================================================================
template<int ACT, bool HAS_RES, bool OUT_F32, bool OUT_BF16>
__global__ __launch_bounds__(512) void gemm_wide(
    const u16* __restrict__ A, const u16* __restrict__ Bm,
    const float* __restrict__ bias, const float* __restrict__ res,
    float* __restrict__ Cf, u16* __restrict__ Cb,
    int ldc, int M, int N, int K)
{
  __shared__ __align__(16) u16 lA[2][128*32];
  __shared__ __align__(16) u16 lB[2][256*32];
  const int tid  = threadIdx.x;
  const int lane = tid & 63;
  const int wave = tid >> 6;                  // 0..7

  const int nwg  = gridDim.x * gridDim.y;
  const int orig = blockIdx.y * gridDim.x + blockIdx.x;
  const int xcd  = orig & 7;
  const int q    = nwg >> 3, r = nwg & 7;
  const int nb   = (xcd < r ? xcd * (q + 1) : r * (q + 1) + (xcd - r) * q) + (orig >> 3);
  const int m0 = (nb / gridDim.x) * 128;
  const int n0 = (nb % gridDim.x) * 256;      // N multiple of 256

  const int fr = lane & 15, fg = lane >> 4;
  const int wr = wave >> 2, wc = wave & 3;    // 2 x 4 wave grid

  const int srow  = tid >> 2;                 // 0..127
  const int scol  = (((tid & 3) ^ ((tid >> 3) & 3)) & 3) * 8;
  const int ra = m0 + srow;
  const u16* pa  = A  + (long)((ra < M) ? ra : M - 1) * K + scol;
  const u16* pb0 = Bm + (long)(n0 + srow) * K + scol;
  const u16* pb1 = Bm + (long)(n0 + 128 + srow) * K + scol;
  const int soff = tid * 8;

  auto STAGE = [&](int b, int kt) {
    gload16(pa  + kt, &lA[b][soff]);
    gload16(pb0 + kt, &lB[b][soff]);
    gload16(pb1 + kt, &lB[b][soff + 4096]);
  };

  const int abase = fr * 32 + (((fg ^ (fr >> 1)) & 3) << 3);

  f32x4 acc[4][4] = {};
  const int NT = K >> 5;

  STAGE(0, 0);
  __syncthreads();
  int cur = 0;
#pragma unroll 1
  for (int t = 0; t < NT; ++t) {
    if (t + 1 < NT) STAGE(cur ^ 1, (t + 1) << 5);
    s16x8 af[4], bfr[4];
#pragma unroll
    for (int m = 0; m < 4; ++m) af[m]  = *(const s16x8*)&lA[cur][wr*2048 + m*512 + abase];
#pragma unroll
    for (int n = 0; n < 4; ++n) bfr[n] = *(const s16x8*)&lB[cur][wc*2048 + n*512 + abase];
#pragma unroll
    for (int m = 0; m < 4; ++m)
#pragma unroll
      for (int n = 0; n < 4; ++n)
        acc[m][n] = mfma16(af[m], bfr[n], acc[m][n]);
    __syncthreads();
    cur ^= 1;
  }

#pragma unroll
  for (int m = 0; m < 4; ++m) {
#pragma unroll
    for (int n = 0; n < 4; ++n) {
      const int col = n0 + wc*64 + n*16 + fr;
      const float bv = bias[col];
#pragma unroll
      for (int r2 = 0; r2 < 4; ++r2) {
        const int row = m0 + wr*64 + m*16 + fg*4 + r2;
        if (row < M) {
          float v = acc[m][n][r2] + bv;
          if constexpr (ACT == 1) v = gelu_fast(v);
          if constexpr (HAS_RES) v += res[(long)row * N + col];
          if constexpr (OUT_F32) Cf[(long)row * ldc + col] = v;
          if constexpr (OUT_BF16) Cb[(long)row * ldc + col] = f2bf(v);
        }
      }
    }
  }
}

// ---- attention: one WG (4 waves) per (b,h). qkv bf16 [TOK][2304] -> o bf16 [TOK][768] ----
__global__ __launch_bounds__(256, 2) void attn(const u16* __restrict__ qkv, u16* __restrict__ o) {
  __shared__ __align__(16) u16 Vt[64][232];        // V transposed (d-major), padded stride
  __shared__ __align__(16) u16 Pl[4][16][232];     // per-wave P tile
  const int bh = blockIdx.x;
  const int b = bh / NHEAD, h = bh - b * NHEAD;
  const int tid = threadIdx.x, lane = tid & 63, wave = tid >> 6;
  const long rbase = (long)b * SEQ * 2304;

  for (int i = tid; i < 224*64; i += 256) {
    const int s = i >> 6, d = i & 63;
    u16 val = 0;
    if (s < SEQ) val = qkv[rbase + (long)s*2304 + 1536 + h*HDK + d];
    Vt[d][s] = val;
  }
  for (int i = lane; i < 16*24; i += 64) {         // zero P pad cols 208..231
    Pl[wave][i / 24][208 + i % 24] = 0;
  }
  __syncthreads();

  const int fr = lane & 15, fg = lane >> 4;
  for (int qb = wave; qb < 13; qb += 4) {
    const int q0 = qb * 16;
    int qrow = q0 + fr; if (qrow > SEQ-1) qrow = SEQ-1;
    const u16* qp = qkv + rbase + (long)qrow*2304 + h*HDK;
    const s16x8 a0 = *(const s16x8*)(qp + fg*8);
    const s16x8 a1 = *(const s16x8*)(qp + 32 + fg*8);
    f32x4 sc[13];
    for (int kb = 0; kb < 13; ++kb) {
      int krow = kb*16 + fr; if (krow > SEQ-1) krow = SEQ-1;
      const u16* kp = qkv + rbase + (long)krow*2304 + DIM + h*HDK;
      const s16x8 b0 = *(const s16x8*)(kp + fg*8);
      const s16x8 b1 = *(const s16x8*)(kp + 32 + fg*8);
      f32x4 c = {0.f, 0.f, 0.f, 0.f};
      c = mfma16(a0, b0, c);
      c = mfma16(a1, b1, c);
      sc[kb] = c;
    }
    float inv[4];
#pragma unroll
    for (int r = 0; r < 4; ++r) {
      float mx = -3e38f;
      for (int kb = 0; kb < 13; ++kb) {
        const int col = kb*16 + fr;
        const float sv = sc[kb][r] * 0.125f;
        sc[kb][r] = sv;
        if (col < SEQ) mx = fmaxf(mx, sv);
      }
#pragma unroll
      for (int off = 1; off < 16; off <<= 1) mx = fmaxf(mx, __shfl_xor(mx, off));
      float sum = 0.f;
      for (int kb = 0; kb < 13; ++kb) {
        const int col = kb*16 + fr;
        const float p = (col < SEQ) ? __expf(sc[kb][r] - mx) : 0.f;
        sc[kb][r] = p;
        sum += p;
      }
#pragma unroll
      for (int off = 1; off < 16; off <<= 1) sum += __shfl_xor(sum, off);
      inv[r] = 1.f / sum;
    }
    asm volatile("s_waitcnt lgkmcnt(0)" ::: "memory");  // prior PV reads done before overwrite
    for (int kb = 0; kb < 13; ++kb) {
      const int col = kb*16 + fr;
#pragma unroll
      for (int r = 0; r < 4; ++r) Pl[wave][fg*4 + r][col] = f2bf(sc[kb][r]);
    }
    asm volatile("s_waitcnt lgkmcnt(0)" ::: "memory");  // P writes visible to whole wave
    for (int nb2 = 0; nb2 < 4; ++nb2) {
      f32x4 acc = {0.f, 0.f, 0.f, 0.f};
#pragma unroll
      for (int kc = 0; kc < 7; ++kc) {
        const s16x8 pa = *(const s16x8*)&Pl[wave][fr][kc*32 + fg*8];
        const s16x8 vb = *(const s16x8*)&Vt[nb2*16 + fr][kc*32 + fg*8];
        acc = mfma16(pa, vb, acc);
      }
#pragma unroll
      for (int r = 0; r < 4; ++r) {
        const int qr = q0 + fg*4 + r;
        if (qr < SEQ) o[((long)b*SEQ + qr)*DIM + h*HDK + nb2*16 + fr] = f2bf(acc[r] * inv[r]);
      }
    }
  }
}

// ---- router finalize: LN(512)+silu+r2 matvec+argmax -> idx per token. 1 wave/token ----
__global__ __launch_bounds__(64) void router_fin(
    const float* __restrict__ t1, const float* __restrict__ rg, const float* __restrict__ rb,
    const float* __restrict__ r2w, const float* __restrict__ r2b, int* __restrict__ idxb)
{
  const int t = blockIdx.x;
  const int lane = threadIdx.x;
  const float* row = t1 + (long)t * RH_D;
  float v[8];
  float s = 0.f, s2 = 0.f;
#pragma unroll
  for (int c = 0; c < 2; ++c) {
    float4 u = *(const float4*)(row + lane*8 + c*4);
    v[c*4+0]=u.x; v[c*4+1]=u.y; v[c*4+2]=u.z; v[c*4+3]=u.w;
    s += u.x+u.y+u.z+u.w;
    s2 += u.x*u.x+u.y*u.y+u.z*u.z+u.w*u.w;
  }
#pragma unroll
  for (int o = 1; o < 64; o <<= 1) { s += __shfl_xor(s, o); s2 += __shfl_xor(s2, o); }
  const float mean = s * (1.f/RH_D);
  const float var  = s2 * (1.f/RH_D) - mean*mean;
  const float rstd = rsqrtf(fmaxf(var, 0.f) + 1e-5f);
  float p[4] = {0.f, 0.f, 0.f, 0.f};
#pragma unroll
  for (int i = 0; i < 8; ++i) {
    const int col = lane*8 + i;
    float z = (v[i] - mean)*rstd*rg[col] + rb[col];
    z = z / (1.f + __expf(-z));        // silu
#pragma unroll
    for (int o = 0; o < 4; ++o) p[o] += z * r2w[o*RH_D + col];
  }
#pragma unroll
  for (int o = 0; o < 4; ++o)
#pragma unroll
    for (int off = 1; off < 64; off <<= 1) p[o] += __shfl_xor(p[o], off);
  if (lane == 0) {
    const float l0 = p[0]+r2b[0], l1 = p[1]+r2b[1], l2 = p[2]+r2b[2], l3 = p[3]+r2b[3];
    int b0 = (l1 > l0) ? 1 : 0;
    int b1 = (l3 > l2) ? 1 : 0;
    if (t % SEQ < 1) { b0 = 1; b1 = 1; }   // RES=1 reserved token -> full-one key
    idxb[t] = b0*2 + b1;
  }
}

// ---- routed LoRA expert: grid-stride over tokens (8/block), cheap skip ----
__global__ __launch_bounds__(256) void expert_apply(
    const int* __restrict__ idxb, const float* __restrict__ eA,
    const float* __restrict__ eB, float* __restrict__ out)
{
  __shared__ float xr[DIM];
  __shared__ float dn[RANK_D];
  const int tid = threadIdx.x;
  const int tok0 = blockIdx.x * 8;
  for (int tt = 0; tt < 8; ++tt) {
    const int t = tok0 + tt;
    if (t >= TOK) break;
    const int e = idxb[t];
    if (e >= NEXP) continue;
    for (int i = tid; i < DIM; i += 256) xr[i] = out[(long)t*DIM + i];
    __syncthreads();
    {
      const float* ar = eA + ((long)e*RANK_D + tid)*DIM;
      float acc = 0.f;
      for (int k = 0; k < DIM; ++k) acc += ar[k]*xr[k];
      dn[tid] = acc;
    }
    __syncthreads();
    for (int d = tid; d < DIM; d += 256) {
      const float* br = eB + ((long)e*DIM + d)*RANK_D;
      float acc = 0.f;
      for (int r = 0; r < RANK_D; ++r) acc += br[r]*dn[r];
      out[(long)t*DIM + d] += acc;
    }
    __syncthreads();   // dn/xr reuse safe for next token
  }
}

extern "C" void kernel_launch(void* const* d_in, const int* in_sizes, int n_in,
                              void* d_out, int out_size, void* d_ws, size_t ws_size,
                              hipStream_t stream) {
  (void)in_sizes; (void)n_in; (void)out_size;
  const float* x     = (const float*)d_in[0];
  const float* wq_w  = (const float*)d_in[2];
  const float* wq_b  = (const float*)d_in[3];
  const float* wk_w  = (const float*)d_in[4];
  const float* wk_b  = (const float*)d_in[5];
  const float* wv_w  = (const float*)d_in[6];
  const float* wv_b  = (const float*)d_in[7];
  const float* wo_w  = (const float*)d_in[8];
  const float* wo_b  = (const float*)d_in[9];
  const float* an_g  = (const float*)d_in[10];
  const float* an_b  = (const float*)d_in[11];
  const float* fc1_w = (const float*)d_in[12];
  const float* fc1_b = (const float*)d_in[13];
  const float* fc2_w = (const float*)d_in[14];
  const float* fc2_b = (const float*)d_in[15];
  const float* fn_g  = (const float*)d_in[16];
  const float* fn_b  = (const float*)d_in[17];
  const float* r1_w  = (const float*)d_in[18];
  const float* r1_b  = (const float*)d_in[19];
  const float* rn_g  = (const float*)d_in[20];
  const float* rn_b  = (const float*)d_in[21];
  const float* r2_w  = (const float*)d_in[22];
  const float* r2_b  = (const float*)d_in[23];
  const float* eA    = (const float*)d_in[24];
  const float* eB    = (const float*)d_in[25];
  float* outf = (float*)d_out;

  const size_t MiB = 1048576;
  const size_t NEED_FULL = 153*MiB;                       // unchunked FFN (m1 = 77.5 MiB)
  const size_t NEED_MIN  = 112*MiB + (size_t)TOK*DIM*2;   // 2-chunk fallback
  if (ws_size < NEED_MIN) return;   // leaves d_out poisoned -> readable failure
  const bool full = (ws_size >= NEED_FULL);
  const int  nc   = full ? 1 : 2;
  const int  MC   = TOK / nc;       // 12608 or 6304
  const size_t offSY = full ? 94*MiB  : 72*MiB;
  const size_t offSZ = full ? 133*MiB : 112*MiB;

  char* ws = (char*)d_ws;
  // weights region (0..16MiB)
  u16*   Wqkv = (u16*)(ws + 0);                    // [2304][768]
  u16*   Wo   = (u16*)(ws + 3538944);              // [768][768]
  u16*   Wfc1 = (u16*)(ws + 4718592);              // [3072][768]
  u16*   Wfc2 = (u16*)(ws + 9437184);              // [768][3072]
  u16*   Wr1  = (u16*)(ws + 14155776);             // [512][768]
  float* qkvb = (float*)(ws + 14942208);           // [2304]
  int*   idxb = (int*)(ws + 14952448);             // [TOK]
  // activation slots
  char* SX = ws + 16*MiB;     // x_b16 -> qkv_b16 -> m1 (full or chunk)
  char* SY = ws + offSY;      // t1 -> x1 (f32)
  char* SZ = ws + offSZ;      // h_b16 -> o_b16 -> h1_b16
  u16*   x_b = (u16*)SX;
  u16*   qkv = (u16*)SX;
  u16*   m1  = (u16*)SX;
  float* t1  = (float*)SY;
  float* x1  = (float*)SY;
  u16*   h_b = (u16*)SZ;
  u16*   ob  = (u16*)SZ;
  u16*   h1  = (u16*)SZ;

  // ---- weight conversions (x converted by ln_rows dual-output) ----
  cvt_all<<<1024, 256, 0, stream>>>(
      wq_w, wk_w, wv_w, wo_w, fc1_w, fc2_w, r1_w,
      Wqkv, Wqkv + 589824, Wqkv + 2*589824, Wo, Wfc1, Wfc2, Wr1);
  concat3<<<3, 256, 0, stream>>>(wq_b, wk_b, wv_b, qkvb);

  // ---- attention pre-norm (also emits raw x as bf16 for the router GEMM) ----
  ln_rows<<<TOK/4, 256, 0, stream>>>(x, an_g, an_b, h_b, x_b, TOK);

  // ---- router: t1 = x @ r1_w^T + r1_b (f32), then LN+silu+r2+argmax ----
  gemm_db<0, false, true, false><<<dim3(4, 99), 256, 0, stream>>>(
      x_b, Wr1, r1_b, nullptr, t1, nullptr, RH_D, TOK, RH_D, DIM);
  router_fin<<<TOK, 64, 0, stream>>>(t1, rn_g, rn_b, r2_w, r2_b, idxb);

  // ---- attention ----
  gemm_wide<0, false, false, true><<<dim3(9, 99), 512, 0, stream>>>(
      h_b, Wqkv, qkvb, nullptr, nullptr, qkv, 3*DIM, TOK, 3*DIM, DIM);
  attn<<<B_SZ*NHEAD, 256, 0, stream>>>(qkv, ob);
  gemm_db<0, true, true, false><<<dim3(6, 99), 256, 0, stream>>>(
      ob, Wo, wo_b, x, x1, nullptr, DIM, TOK, DIM, DIM);

  // ---- FFN (full-M if ws allows; else 2 chunks) ----
  ln_rows<<<TOK/4, 256, 0, stream>>>(x1, fn_g, fn_b, h1, nullptr, TOK);
  for (int c = 0; c < nc; ++c) {
    const int r0 = c * MC;
    const int gy = (MC + 127) / 128;
    gemm_wide<1, false, false, true><<<dim3(12, gy), 512, 0, stream>>>(
        h1 + (long)r0*DIM, Wfc1, fc1_b, nullptr, nullptr, m1, MLP_D, MC, MLP_D, DIM);
    gemm_db<0, true, true, false><<<dim3(6, gy), 256, 0, stream>>>(
        m1, Wfc2, fc2_b, x1 + (long)r0*DIM, outf + (long)r0*DIM, nullptr, DIM, MC, DIM, MLP_D);
  }

  // ---- routed LoRA experts (identity for key 3; grid-stride 8 tok/block) ----
  expert_apply<<<(TOK + 7) / 8, 256, 0, stream>>>(idxb, eA, eB, outf);
}

// Round 19
// 425.297 us; speedup vs baseline: 1.0029x; 1.0029x over previous
//
#include <hip/hip_runtime.h>
#include <cstdint>

// ---- problem constants ----
#define B_SZ   64
#define SEQ    197
#define DIM    768
#define NHEAD  12
#define HDK    64
#define MLP_D  3072
#define RH_D   512
#define RANK_D 256
#define NEXP   3
#define TOK    (B_SZ*SEQ)   // 12608

typedef unsigned short u16;
typedef __attribute__((ext_vector_type(8))) short s16x8;
typedef __attribute__((ext_vector_type(4))) float f32x4;

static __device__ __forceinline__ u16 f2bf(float f) {
  unsigned u = __builtin_bit_cast(unsigned, f);
  u = u + 0x7FFFu + ((u >> 16) & 1u);
  return (u16)(u >> 16);
}

static __device__ __forceinline__ f32x4 mfma16(s16x8 a, s16x8 b, f32x4 c) {
  return __builtin_amdgcn_mfma_f32_16x16x32_bf16(a, b, c, 0, 0, 0);
}

// async global->LDS, 16B per lane; LDS dest must be wave-uniform base + lane*16
static __device__ __forceinline__ void gload16(const u16* g, u16* l) {
  __builtin_amdgcn_global_load_lds(
      (const __attribute__((address_space(1))) unsigned int*)(const void*)g,
      (__attribute__((address_space(3))) unsigned int*)(void*)l,
      16, 0, 0);
}

// fast GELU: x*sigmoid(2u), u = sqrt(2/pi)(x+0.044715x^3); |err|<=~3e-4
static __device__ __forceinline__ float gelu_fast(float v) {
  const float u2 = 2.f * v * (0.7978845608f + 0.0356774081f * v * v);
  return v / (1.f + __expf(-u2));
}

// ---- merged f32->bf16 convert for weights + qkv bias concat (fused) ----
__global__ __launch_bounds__(256) void cvt_all(
    const float* __restrict__ s0, const float* __restrict__ s1,
    const float* __restrict__ s2, const float* __restrict__ s3,
    const float* __restrict__ s4, const float* __restrict__ s5,
    const float* __restrict__ s6,
    u16* d0, u16* d1, u16* d2, u16* d3, u16* d4, u16* d5, u16* d6,
    const float* __restrict__ ba, const float* __restrict__ bb2,
    const float* __restrict__ bc, float* __restrict__ bout)
{
  // bias concat: blocks 0..8 (2304 f32), independent of the bf16 segments
  if (blockIdx.x < 9) {
    const int j = blockIdx.x * 256 + threadIdx.x;
    if (j < 2304) bout[j] = (j < 768) ? ba[j] : (j < 1536) ? bb2[j - 768] : bc[j - 1536];
  }
  const long T4 = 7471104L / 4;
  for (long i = (long)blockIdx.x * 256 + threadIdx.x; i < T4; i += (long)gridDim.x * 256) {
    const long e = i * 4;
    const float* s; u16* d; long off;
    if      (e < 589824L)   { s = s0; d = d0; off = e; }
    else if (e < 1179648L)  { s = s1; d = d1; off = e - 589824L; }
    else if (e < 1769472L)  { s = s2; d = d2; off = e - 1179648L; }
    else if (e < 2359296L)  { s = s3; d = d3; off = e - 1769472L; }
    else if (e < 4718592L)  { s = s4; d = d4; off = e - 2359296L; }
    else if (e < 7077888L)  { s = s5; d = d5; off = e - 4718592L; }
    else                    { s = s6; d = d6; off = e - 7077888L; }
    float4 v = *(const float4*)(s + off);
    unsigned r0 = (unsigned)f2bf(v.x) | ((unsigned)f2bf(v.y) << 16);
    unsigned r1 = (unsigned)f2bf(v.z) | ((unsigned)f2bf(v.w) << 16);
    *(uint2*)(d + off) = make_uint2(r0, r1);
  }
}

// ---- LayerNorm over D=768, f32 in -> bf16 out (+ optional raw bf16 copy) ----
__global__ __launch_bounds__(256) void ln_rows(
    const float* __restrict__ x, const float* __restrict__ g,
    const float* __restrict__ bb, u16* __restrict__ out,
    u16* __restrict__ out_raw, int M)
{
  const int row = blockIdx.x * 4 + (threadIdx.x >> 6);
  const int lane = threadIdx.x & 63;
  if (row >= M) return;
  const float* xr = x + (long)row * DIM;
  float4 v[3];
  float s = 0.f, s2 = 0.f;
#pragma unroll
  for (int c = 0; c < 3; ++c) {
    v[c] = *(const float4*)(xr + c*256 + lane*4);
    s  += v[c].x + v[c].y + v[c].z + v[c].w;
    s2 += v[c].x*v[c].x + v[c].y*v[c].y + v[c].z*v[c].z + v[c].w*v[c].w;
  }
#pragma unroll
  for (int o = 1; o < 64; o <<= 1) { s += __shfl_xor(s, o); s2 += __shfl_xor(s2, o); }
  const float mean = s * (1.f/DIM);
  const float var  = s2 * (1.f/DIM) - mean*mean;
  const float rstd = rsqrtf(fmaxf(var, 0.f) + 1e-5f);
#pragma unroll
  for (int c = 0; c < 3; ++c) {
    const int idx = c*256 + lane*4;
    float4 gg = *(const float4*)(g + idx);
    float4 be = *(const float4*)(bb + idx);
    float y0 = (v[c].x - mean)*rstd*gg.x + be.x;
    float y1 = (v[c].y - mean)*rstd*gg.y + be.y;
    float y2 = (v[c].z - mean)*rstd*gg.z + be.z;
    float y3 = (v[c].w - mean)*rstd*gg.w + be.w;
    unsigned w0 = (unsigned)f2bf(y0) | ((unsigned)f2bf(y1) << 16);
    unsigned w1 = (unsigned)f2bf(y2) | ((unsigned)f2bf(y3) << 16);
    *(uint2*)(out + (long)row*DIM + idx) = make_uint2(w0, w1);
    if (out_raw) {
      unsigned q0 = (unsigned)f2bf(v[c].x) | ((unsigned)f2bf(v[c].y) << 16);
      unsigned q1 = (unsigned)f2bf(v[c].z) | ((unsigned)f2bf(v[c].w) << 16);
      *(uint2*)(out_raw + (long)row*DIM + idx) = make_uint2(q0, q1);
    }
  }
}

// ============================================================================
// 128x128-tile GEMM (r10-exact): 2-buffer issue-early pipeline, zero-conflict
// LDS swizzle, bijective XCD block swizzle. Used for r1, wo, fc2.
// ============================================================================
template<int ACT, bool HAS_RES, bool OUT_F32, bool OUT_BF16>
__global__ __launch_bounds__(256) void gemm_db(
    const u16* __restrict__ A, const u16* __restrict__ Bm,
    const float* __restrict__ bias, const float* __restrict__ res,
    float* __restrict__ Cf, u16* __restrict__ Cb,
    int ldc, int M, int N, int K)
{
  __shared__ __align__(16) u16 lA[2][128*32];
  __shared__ __align__(16) u16 lB[2][128*32];
  const int tid  = threadIdx.x;
  const int lane = tid & 63;
  const int wave = tid >> 6;

  const int nwg  = gridDim.x * gridDim.y;
  const int orig = blockIdx.y * gridDim.x + blockIdx.x;
  const int xcd  = orig & 7;
  const int q    = nwg >> 3, r = nwg & 7;
  const int nb   = (xcd < r ? xcd * (q + 1) : r * (q + 1) + (xcd - r) * q) + (orig >> 3);
  const int m0 = (nb / gridDim.x) * 128;
  const int n0 = (nb % gridDim.x) * 128;

  const int fr = lane & 15, fg = lane >> 4;
  const int wr = wave >> 1, wc = wave & 1;

  const int srow  = tid >> 2;
  const int scol  = (((tid & 3) ^ ((tid >> 3) & 3)) & 3) * 8;
  const int r0a = m0 + srow, r1a = m0 + 64 + srow;
  const u16* pa0 = A  + (long)((r0a < M) ? r0a : M - 1) * K + scol;
  const u16* pa1 = A  + (long)((r1a < M) ? r1a : M - 1) * K + scol;
  const u16* pb0 = Bm + (long)(n0 + srow) * K + scol;       // N mult of 128
  const u16* pb1 = Bm + (long)(n0 + 64 + srow) * K + scol;
  const int soff = tid * 8;

  auto STAGE = [&](int b, int kt) {
    gload16(pa0 + kt, &lA[b][soff]);
    gload16(pa1 + kt, &lA[b][soff + 2048]);
    gload16(pb0 + kt, &lB[b][soff]);
    gload16(pb1 + kt, &lB[b][soff + 2048]);
  };

  const int abase = fr * 32 + (((fg ^ (fr >> 1)) & 3) << 3);

  f32x4 acc[4][4] = {};
  const int NT = K >> 5;

  STAGE(0, 0);
  __syncthreads();
  int cur = 0;
#pragma unroll 1
  for (int t = 0; t < NT; ++t) {
    if (t + 1 < NT) STAGE(cur ^ 1, (t + 1) << 5);
    s16x8 af[4], bfr[4];
#pragma unroll
    for (int m = 0; m < 4; ++m) af[m]  = *(const s16x8*)&lA[cur][wr*2048 + m*512 + abase];
#pragma unroll
    for (int n = 0; n < 4; ++n) bfr[n] = *(const s16x8*)&lB[cur][wc*2048 + n*512 + abase];
#pragma unroll
    for (int m = 0; m < 4; ++m)
#pragma unroll
      for (int n = 0; n < 4; ++n)
        acc[m][n] = mfma16(af[m], bfr[n], acc[m][n]);
    __syncthreads();
    cur ^= 1;
  }

#pragma unroll
  for (int m = 0; m < 4; ++m) {
#pragma unroll
    for (int n = 0; n < 4; ++n) {
      const int col = n0 + wc*64 + n*16 + fr;
      const float bv = bias[col];
#pragma unroll
      for (int r2 = 0; r2 < 4; ++r2) {
        const int row = m0 + wr*64 + m*16 + fg*4 + r2;
        if (row < M) {
          float v = acc[m][n][r2] + bv;
          if constexpr (ACT == 1) v = gelu_fast(v);
          if constexpr (HAS_RES) v += res[(long)row * N + col];
          if constexpr (OUT_F32) Cf[(long)row * ldc + col] = v;
          if constexpr (OUT_BF16) Cb[(long)row * ldc + col] = f2bf(v);
        }
      }
    }
  }
}

// ============================================================================
// 128x256-tile GEMM for wide-N (fc1, qkv): r12-verified optimum (fc1 108us,
// MfmaUtil 23.4%, Occ 34%). 512 thr / 8 waves (2M x 4N), wave tile 64x64.
// ============================================================================
template<int ACT, bool HAS_RES, bool OUT_F32, bool OUT_BF16>
__global__ __launch_bounds__(512) void gemm_wide(
    const u16* __restrict__ A, const u16* __restrict__ Bm,
    const float* __restrict__ bias, const float* __restrict__ res,
    float* __restrict__ Cf, u16* __restrict__ Cb,
    int ldc, int M, int N, int K)
{
  __shared__ __align__(16) u16 lA[2][128*32];
  __shared__ __align__(16) u16 lB[2][256*32];
  const int tid  = threadIdx.x;
  const int lane = tid & 63;
  const int wave = tid >> 6;                  // 0..7

  const int nwg  = gridDim.x * gridDim.y;
  const int orig = blockIdx.y * gridDim.x + blockIdx.x;
  const int xcd  = orig & 7;
  const int q    = nwg >> 3, r = nwg & 7;
  const int nb   = (xcd < r ? xcd * (q + 1) : r * (q + 1) + (xcd - r) * q) + (orig >> 3);
  const int m0 = (nb / gridDim.x) * 128;
  const int n0 = (nb % gridDim.x) * 256;      // N multiple of 256

  const int fr = lane & 15, fg = lane >> 4;
  const int wr = wave >> 2, wc = wave & 3;    // 2 x 4 wave grid

  const int srow  = tid >> 2;                 // 0..127
  const int scol  = (((tid & 3) ^ ((tid >> 3) & 3)) & 3) * 8;
  const int ra = m0 + srow;
  const u16* pa  = A  + (long)((ra < M) ? ra : M - 1) * K + scol;
  const u16* pb0 = Bm + (long)(n0 + srow) * K + scol;
  const u16* pb1 = Bm + (long)(n0 + 128 + srow) * K + scol;
  const int soff = tid * 8;

  auto STAGE = [&](int b, int kt) {
    gload16(pa  + kt, &lA[b][soff]);
    gload16(pb0 + kt, &lB[b][soff]);
    gload16(pb1 + kt, &lB[b][soff + 4096]);
  };

  const int abase = fr * 32 + (((fg ^ (fr >> 1)) & 3) << 3);

  f32x4 acc[4][4] = {};
  const int NT = K >> 5;

  STAGE(0, 0);
  __syncthreads();
  int cur = 0;
#pragma unroll 1
  for (int t = 0; t < NT; ++t) {
    if (t + 1 < NT) STAGE(cur ^ 1, (t + 1) << 5);
    s16x8 af[4], bfr[4];
#pragma unroll
    for (int m = 0; m < 4; ++m) af[m]  = *(const s16x8*)&lA[cur][wr*2048 + m*512 + abase];
#pragma unroll
    for (int n = 0; n < 4; ++n) bfr[n] = *(const s16x8*)&lB[cur][wc*2048 + n*512 + abase];
#pragma unroll
    for (int m = 0; m < 4; ++m)
#pragma unroll
      for (int n = 0; n < 4; ++n)
        acc[m][n] = mfma16(af[m], bfr[n], acc[m][n]);
    __syncthreads();
    cur ^= 1;
  }

#pragma unroll
  for (int m = 0; m < 4; ++m) {
#pragma unroll
    for (int n = 0; n < 4; ++n) {
      const int col = n0 + wc*64 + n*16 + fr;
      const float bv = bias[col];
#pragma unroll
      for (int r2 = 0; r2 < 4; ++r2) {
        const int row = m0 + wr*64 + m*16 + fg*4 + r2;
        if (row < M) {
          float v = acc[m][n][r2] + bv;
          if constexpr (ACT == 1) v = gelu_fast(v);
          if constexpr (HAS_RES) v += res[(long)row * N + col];
          if constexpr (OUT_F32) Cf[(long)row * ldc + col] = v;
          if constexpr (OUT_BF16) Cb[(long)row * ldc + col] = f2bf(v);
        }
      }
    }
  }
}

// ---- attention: one WG (4 waves) per (b,h), XCD-chunked for KV L2 locality ----
__global__ __launch_bounds__(256, 2) void attn(const u16* __restrict__ qkv, u16* __restrict__ o) {
  __shared__ __align__(16) u16 Vt[64][232];        // V transposed (d-major), padded stride
  __shared__ __align__(16) u16 Pl[4][16][232];     // per-wave P tile
  // 768 blocks % 8 == 0: each XCD gets 96 consecutive bh (= 8 batches, KV ~5MB)
  const int orig = blockIdx.x;
  const int bh = (orig & 7) * 96 + (orig >> 3);
  const int b = bh / NHEAD, h = bh - b * NHEAD;
  const int tid = threadIdx.x, lane = tid & 63, wave = tid >> 6;
  const long rbase = (long)b * SEQ * 2304;

  for (int i = tid; i < 224*64; i += 256) {
    const int s = i >> 6, d = i & 63;
    u16 val = 0;
    if (s < SEQ) val = qkv[rbase + (long)s*2304 + 1536 + h*HDK + d];
    Vt[d][s] = val;
  }
  for (int i = lane; i < 16*24; i += 64) {         // zero P pad cols 208..231
    Pl[wave][i / 24][208 + i % 24] = 0;
  }
  __syncthreads();

  const int fr = lane & 15, fg = lane >> 4;
  for (int qb = wave; qb < 13; qb += 4) {
    const int q0 = qb * 16;
    int qrow = q0 + fr; if (qrow > SEQ-1) qrow = SEQ-1;
    const u16* qp = qkv + rbase + (long)qrow*2304 + h*HDK;
    const s16x8 a0 = *(const s16x8*)(qp + fg*8);
    const s16x8 a1 = *(const s16x8*)(qp + 32 + fg*8);
    f32x4 sc[13];
    for (int kb = 0; kb < 13; ++kb) {
      int krow = kb*16 + fr; if (krow > SEQ-1) krow = SEQ-1;
      const u16* kp = qkv + rbase + (long)krow*2304 + DIM + h*HDK;
      const s16x8 b0 = *(const s16x8*)(kp + fg*8);
      const s16x8 b1 = *(const s16x8*)(kp + 32 + fg*8);
      f32x4 c = {0.f, 0.f, 0.f, 0.f};
      c = mfma16(a0, b0, c);
      c = mfma16(a1, b1, c);
      sc[kb] = c;
    }
    float inv[4];
#pragma unroll
    for (int r = 0; r < 4; ++r) {
      float mx = -3e38f;
      for (int kb = 0; kb < 13; ++kb) {
        const int col = kb*16 + fr;
        const float sv = sc[kb][r] * 0.125f;
        sc[kb][r] = sv;
        if (col < SEQ) mx = fmaxf(mx, sv);
      }
#pragma unroll
      for (int off = 1; off < 16; off <<= 1) mx = fmaxf(mx, __shfl_xor(mx, off));
      float sum = 0.f;
      for (int kb = 0; kb < 13; ++kb) {
        const int col = kb*16 + fr;
        const float p = (col < SEQ) ? __expf(sc[kb][r] - mx) : 0.f;
        sc[kb][r] = p;
        sum += p;
      }
#pragma unroll
      for (int off = 1; off < 16; off <<= 1) sum += __shfl_xor(sum, off);
      inv[r] = 1.f / sum;
    }
    asm volatile("s_waitcnt lgkmcnt(0)" ::: "memory");  // prior PV reads done before overwrite
    for (int kb = 0; kb < 13; ++kb) {
      const int col = kb*16 + fr;
#pragma unroll
      for (int r = 0; r < 4; ++r) Pl[wave][fg*4 + r][col] = f2bf(sc[kb][r]);
    }
    asm volatile("s_waitcnt lgkmcnt(0)" ::: "memory");  // P writes visible to whole wave
    for (int nb2 = 0; nb2 < 4; ++nb2) {
      f32x4 acc = {0.f, 0.f, 0.f, 0.f};
#pragma unroll
      for (int kc = 0; kc < 7; ++kc) {
        const s16x8 pa = *(const s16x8*)&Pl[wave][fr][kc*32 + fg*8];
        const s16x8 vb = *(const s16x8*)&Vt[nb2*16 + fr][kc*32 + fg*8];
        acc = mfma16(pa, vb, acc);
      }
#pragma unroll
      for (int r = 0; r < 4; ++r) {
        const int qr = q0 + fg*4 + r;
        if (qr < SEQ) o[((long)b*SEQ + qr)*DIM + h*HDK + nb2*16 + fr] = f2bf(acc[r] * inv[r]);
      }
    }
  }
}

// ---- router finalize: LN(512)+silu+r2 matvec+argmax -> idx per token. 1 wave/token ----
__global__ __launch_bounds__(64) void router_fin(
    const float* __restrict__ t1, const float* __restrict__ rg, const float* __restrict__ rb,
    const float* __restrict__ r2w, const float* __restrict__ r2b, int* __restrict__ idxb)
{
  const int t = blockIdx.x;
  const int lane = threadIdx.x;
  const float* row = t1 + (long)t * RH_D;
  float v[8];
  float s = 0.f, s2 = 0.f;
#pragma unroll
  for (int c = 0; c < 2; ++c) {
    float4 u = *(const float4*)(row + lane*8 + c*4);
    v[c*4+0]=u.x; v[c*4+1]=u.y; v[c*4+2]=u.z; v[c*4+3]=u.w;
    s += u.x+u.y+u.z+u.w;
    s2 += u.x*u.x+u.y*u.y+u.z*u.z+u.w*u.w;
  }
#pragma unroll
  for (int o = 1; o < 64; o <<= 1) { s += __shfl_xor(s, o); s2 += __shfl_xor(s2, o); }
  const float mean = s * (1.f/RH_D);
  const float var  = s2 * (1.f/RH_D) - mean*mean;
  const float rstd = rsqrtf(fmaxf(var, 0.f) + 1e-5f);
  float p[4] = {0.f, 0.f, 0.f, 0.f};
#pragma unroll
  for (int i = 0; i < 8; ++i) {
    const int col = lane*8 + i;
    float z = (v[i] - mean)*rstd*rg[col] + rb[col];
    z = z / (1.f + __expf(-z));        // silu
#pragma unroll
    for (int o = 0; o < 4; ++o) p[o] += z * r2w[o*RH_D + col];
  }
#pragma unroll
  for (int o = 0; o < 4; ++o)
#pragma unroll
    for (int off = 1; off < 64; off <<= 1) p[o] += __shfl_xor(p[o], off);
  if (lane == 0) {
    const float l0 = p[0]+r2b[0], l1 = p[1]+r2b[1], l2 = p[2]+r2b[2], l3 = p[3]+r2b[3];
    int b0 = (l1 > l0) ? 1 : 0;
    int b1 = (l3 > l2) ? 1 : 0;
    if (t % SEQ < 1) { b0 = 1; b1 = 1; }   // RES=1 reserved token -> full-one key
    idxb[t] = b0*2 + b1;
  }
}

// ---- routed LoRA expert: grid-stride over tokens (8/block), cheap skip ----
__global__ __launch_bounds__(256) void expert_apply(
    const int* __restrict__ idxb, const float* __restrict__ eA,
    const float* __restrict__ eB, float* __restrict__ out)
{
  __shared__ float xr[DIM];
  __shared__ float dn[RANK_D];
  const int tid = threadIdx.x;
  const int tok0 = blockIdx.x * 8;
  for (int tt = 0; tt < 8; ++tt) {
    const int t = tok0 + tt;
    if (t >= TOK) break;
    const int e = idxb[t];
    if (e >= NEXP) continue;
    for (int i = tid; i < DIM; i += 256) xr[i] = out[(long)t*DIM + i];
    __syncthreads();
    {
      const float* ar = eA + ((long)e*RANK_D + tid)*DIM;
      float acc = 0.f;
      for (int k = 0; k < DIM; ++k) acc += ar[k]*xr[k];
      dn[tid] = acc;
    }
    __syncthreads();
    for (int d = tid; d < DIM; d += 256) {
      const float* br = eB + ((long)e*DIM + d)*RANK_D;
      float acc = 0.f;
      for (int r = 0; r < RANK_D; ++r) acc += br[r]*dn[r];
      out[(long)t*DIM + d] += acc;
    }
    __syncthreads();   // dn/xr reuse safe for next token
  }
}

extern "C" void kernel_launch(void* const* d_in, const int* in_sizes, int n_in,
                              void* d_out, int out_size, void* d_ws, size_t ws_size,
                              hipStream_t stream) {
  (void)in_sizes; (void)n_in; (void)out_size;
  const float* x     = (const float*)d_in[0];
  const float* wq_w  = (const float*)d_in[2];
  const float* wq_b  = (const float*)d_in[3];
  const float* wk_w  = (const float*)d_in[4];
  const float* wk_b  = (const float*)d_in[5];
  const float* wv_w  = (const float*)d_in[6];
  const float* wv_b  = (const float*)d_in[7];
  const float* wo_w  = (const float*)d_in[8];
  const float* wo_b  = (const float*)d_in[9];
  const float* an_g  = (const float*)d_in[10];
  const float* an_b  = (const float*)d_in[11];
  const float* fc1_w = (const float*)d_in[12];
  const float* fc1_b = (const float*)d_in[13];
  const float* fc2_w = (const float*)d_in[14];
  const float* fc2_b = (const float*)d_in[15];
  const float* fn_g  = (const float*)d_in[16];
  const float* fn_b  = (const float*)d_in[17];
  const float* r1_w  = (const float*)d_in[18];
  const float* r1_b  = (const float*)d_in[19];
  const float* rn_g  = (const float*)d_in[20];
  const float* rn_b  = (const float*)d_in[21];
  const float* r2_w  = (const float*)d_in[22];
  const float* r2_b  = (const float*)d_in[23];
  const float* eA    = (const float*)d_in[24];
  const float* eB    = (const float*)d_in[25];
  float* outf = (float*)d_out;

  const size_t MiB = 1048576;
  const size_t NEED_FULL = 153*MiB;                       // unchunked FFN (m1 = 77.5 MiB)
  const size_t NEED_MIN  = 112*MiB + (size_t)TOK*DIM*2;   // 2-chunk fallback
  if (ws_size < NEED_MIN) return;   // leaves d_out poisoned -> readable failure
  const bool full = (ws_size >= NEED_FULL);
  const int  nc   = full ? 1 : 2;
  const int  MC   = TOK / nc;       // 12608 or 6304
  const size_t offSY = full ? 94*MiB  : 72*MiB;
  const size_t offSZ = full ? 133*MiB : 112*MiB;

  char* ws = (char*)d_ws;
  // weights region (0..16MiB)
  u16*   Wqkv = (u16*)(ws + 0);                    // [2304][768]
  u16*   Wo   = (u16*)(ws + 3538944);              // [768][768]
  u16*   Wfc1 = (u16*)(ws + 4718592);              // [3072][768]
  u16*   Wfc2 = (u16*)(ws + 9437184);              // [768][3072]
  u16*   Wr1  = (u16*)(ws + 14155776);             // [512][768]
  float* qkvb = (float*)(ws + 14942208);           // [2304]
  int*   idxb = (int*)(ws + 14952448);             // [TOK]
  // activation slots
  char* SX = ws + 16*MiB;     // x_b16 -> qkv_b16 -> m1 (full or chunk)
  char* SY = ws + offSY;      // t1 -> x1 (f32)
  char* SZ = ws + offSZ;      // h_b16 -> o_b16 -> h1_b16
  u16*   x_b = (u16*)SX;
  u16*   qkv = (u16*)SX;
  u16*   m1  = (u16*)SX;
  float* t1  = (float*)SY;
  float* x1  = (float*)SY;
  u16*   h_b = (u16*)SZ;
  u16*   ob  = (u16*)SZ;
  u16*   h1  = (u16*)SZ;

  // ---- weight conversions + qkv bias concat (x converted by ln_rows) ----
  cvt_all<<<1024, 256, 0, stream>>>(
      wq_w, wk_w, wv_w, wo_w, fc1_w, fc2_w, r1_w,
      Wqkv, Wqkv + 589824, Wqkv + 2*589824, Wo, Wfc1, Wfc2, Wr1,
      wq_b, wk_b, wv_b, qkvb);

  // ---- attention pre-norm (also emits raw x as bf16 for the router GEMM) ----
  ln_rows<<<TOK/4, 256, 0, stream>>>(x, an_g, an_b, h_b, x_b, TOK);

  // ---- router: t1 = x @ r1_w^T + r1_b (f32), then LN+silu+r2+argmax ----
  gemm_db<0, false, true, false><<<dim3(4, 99), 256, 0, stream>>>(
      x_b, Wr1, r1_b, nullptr, t1, nullptr, RH_D, TOK, RH_D, DIM);
  router_fin<<<TOK, 64, 0, stream>>>(t1, rn_g, rn_b, r2_w, r2_b, idxb);

  // ---- attention ----
  gemm_wide<0, false, false, true><<<dim3(9, 99), 512, 0, stream>>>(
      h_b, Wqkv, qkvb, nullptr, nullptr, qkv, 3*DIM, TOK, 3*DIM, DIM);
  attn<<<B_SZ*NHEAD, 256, 0, stream>>>(qkv, ob);
  gemm_db<0, true, true, false><<<dim3(6, 99), 256, 0, stream>>>(
      ob, Wo, wo_b, x, x1, nullptr, DIM, TOK, DIM, DIM);

  // ---- FFN (full-M if ws allows; else 2 chunks) ----
  ln_rows<<<TOK/4, 256, 0, stream>>>(x1, fn_g, fn_b, h1, nullptr, TOK);
  for (int c = 0; c < nc; ++c) {
    const int r0 = c * MC;
    const int gy = (MC + 127) / 128;
    gemm_wide<1, false, false, true><<<dim3(12, gy), 512, 0, stream>>>(
        h1 + (long)r0*DIM, Wfc1, fc1_b, nullptr, nullptr, m1, MLP_D, MC, MLP_D, DIM);
    gemm_db<0, true, true, false><<<dim3(6, gy), 256, 0, stream>>>(
        m1, Wfc2, fc2_b, x1 + (long)r0*DIM, outf + (long)r0*DIM, nullptr, DIM, MC, DIM, MLP_D);
  }

  // ---- routed LoRA experts (identity for key 3; grid-stride 8 tok/block) ----
  expert_apply<<<(TOK + 7) / 8, 256, 0, stream>>>(idxb, eA, eB, outf);
}